// Round 1
// baseline (724.219 us; speedup 1.0000x reference)
//
#include <hip/hip_runtime.h>
#include <hip/hip_bf16.h>
#include <math.h>

#define SEQ   2048
#define DDIM  128
#define NBH   32
#define KVB   64
#define QTILE 64
// scale = 1/sqrt(128); fold log2(e) so we can use exp2 everywhere
#define QSCALE (0.08838834764831845f * 1.4426950408889634f)

typedef __bf16 bf16x8 __attribute__((ext_vector_type(8)));
typedef float  f32x4  __attribute__((ext_vector_type(4)));

// Swizzles: XOR byte bits 4..6 with 3 bits of the row index so that b128
// reads (16 lanes, same column-range, different rows) spread over 8 bank-quads.
__device__ __forceinline__ int swz9(int b) { return b ^ (((b >> 9) & 7) << 4); } // Ks: byte = key*256 + d*2
__device__ __forceinline__ int swz8(int b) { return b ^ (((b >> 8) & 7) << 4); } // Vt/P: byte = row*128 + col*2

__device__ __forceinline__ bf16x8 cvt8(float4 a, float4 b, float s) {
    bf16x8 v;
    v[0] = (__bf16)(a.x * s); v[1] = (__bf16)(a.y * s);
    v[2] = (__bf16)(a.z * s); v[3] = (__bf16)(a.w * s);
    v[4] = (__bf16)(b.x * s); v[5] = (__bf16)(b.y * s);
    v[6] = (__bf16)(b.z * s); v[7] = (__bf16)(b.w * s);
    return v;
}

__global__ __launch_bounds__(256, 4)
void attn_fwd_kernel(const float* __restrict__ Q, const float* __restrict__ K,
                     const float* __restrict__ V, float* __restrict__ Out) {
    // LDS: Ks [64 keys][128 d] bf16 (16KB) | Vt [128 d][64 keys] bf16 (16KB)
    //      P  [4 waves][16 rows][64 keys] bf16 (8KB)
    __shared__ __align__(16) unsigned char lds[16384 + 16384 + 4 * 2048];
    unsigned char* KsB = lds;
    unsigned char* VtB = lds + 16384;

    const int tid  = threadIdx.x;
    const int lane = tid & 63;
    const int w    = tid >> 6;
    const int l15  = lane & 15;
    const int g    = lane >> 4;

    const int qt = blockIdx.x;
    const int bh = blockIdx.y;
    const long long base = (long long)bh * SEQ * DDIM;

    const float* Qb = Q + base + (long long)(qt * QTILE + w * 16) * DDIM;
    const float* Kb = K + base;
    const float* Vb = V + base;
    unsigned char* PB = lds + 32768 + w * 2048;

    // ---- Q fragments (A-layout): lane holds row=l15, d = ks*32 + g*8 + j ----
    bf16x8 qf[4];
#pragma unroll
    for (int ks = 0; ks < 4; ++ks) {
        const float* qp = Qb + l15 * DDIM + ks * 32 + g * 8;
        float4 a = *(const float4*)qp;
        float4 b = *(const float4*)(qp + 4);
        qf[ks] = cvt8(a, b, QSCALE);  // pre-scale Q: scores come out in log2 units
    }

    // ---- accumulators ----
    f32x4 o[8];
#pragma unroll
    for (int cb = 0; cb < 8; ++cb) { o[cb][0] = 0.f; o[cb][1] = 0.f; o[cb][2] = 0.f; o[cb][3] = 0.f; }
    float m_r[4] = { -INFINITY, -INFINITY, -INFINITY, -INFINITY };
    float l_r[4] = { 0.f, 0.f, 0.f, 0.f };

    for (int kt = 0; kt < SEQ / KVB; ++kt) {
        __syncthreads();  // previous iteration's LDS reads done before restaging

        // ---- stage K tile: [64][128] bf16, swizzled; 16B chunks, coalesced ----
#pragma unroll
        for (int it = 0; it < 4; ++it) {
            int chunk = tid + it * 256;          // 0..1023
            int key = chunk >> 4;
            int dc  = (chunk & 15) * 8;
            const float* kp = Kb + (long long)(kt * KVB + key) * DDIM + dc;
            float4 a = *(const float4*)kp;
            float4 b = *(const float4*)(kp + 4);
            *(bf16x8*)(KsB + swz9(key * 256 + dc * 2)) = cvt8(a, b, 1.0f);
        }

        // ---- stage V transposed: Vt[d][key] bf16, swizzled ----
#pragma unroll
        for (int it = 0; it < 8; ++it) {
            int task = w + it * 4;               // 0..31
            int kq = task >> 1;
            int dh = task & 1;
            int key = kq * 4 + g;
            int d0  = dh * 64 + l15 * 4;
            const float* vp = Vb + (long long)(kt * KVB + key) * DDIM + d0;
            float4 a = *(const float4*)vp;
            *(__bf16*)(VtB + swz8((d0 + 0) * 128 + key * 2)) = (__bf16)a.x;
            *(__bf16*)(VtB + swz8((d0 + 1) * 128 + key * 2)) = (__bf16)a.y;
            *(__bf16*)(VtB + swz8((d0 + 2) * 128 + key * 2)) = (__bf16)a.z;
            *(__bf16*)(VtB + swz8((d0 + 3) * 128 + key * 2)) = (__bf16)a.w;
        }
        __syncthreads();

        // ---- QK^T: scores for 16 q-rows x 64 keys (4 col-blocks) ----
        f32x4 sc[4];
#pragma unroll
        for (int c = 0; c < 4; ++c) {
            f32x4 acc; acc[0] = 0.f; acc[1] = 0.f; acc[2] = 0.f; acc[3] = 0.f;
#pragma unroll
            for (int ks = 0; ks < 4; ++ks) {
                int byte = (c * 16 + l15) * 256 + (ks * 32 + g * 8) * 2;
                bf16x8 bf = *(const bf16x8*)(KsB + swz9(byte));
                acc = __builtin_amdgcn_mfma_f32_16x16x32_bf16(qf[ks], bf, acc, 0, 0, 0);
            }
            sc[c] = acc;
        }

        // ---- online softmax (per q-row r; row-reduce over lanes 0..15 of group) ----
#pragma unroll
        for (int r = 0; r < 4; ++r) {
            float s0 = sc[0][r], s1 = sc[1][r], s2 = sc[2][r], s3 = sc[3][r];
            float mx = fmaxf(fmaxf(s0, s1), fmaxf(s2, s3));
            mx = fmaxf(mx, __shfl_xor(mx, 1));
            mx = fmaxf(mx, __shfl_xor(mx, 2));
            mx = fmaxf(mx, __shfl_xor(mx, 4));
            mx = fmaxf(mx, __shfl_xor(mx, 8));
            float mold = m_r[r];
            float mnew = fmaxf(mold, mx);
            float alpha = __builtin_amdgcn_exp2f(mold - mnew);
            float p0 = __builtin_amdgcn_exp2f(s0 - mnew);
            float p1 = __builtin_amdgcn_exp2f(s1 - mnew);
            float p2 = __builtin_amdgcn_exp2f(s2 - mnew);
            float p3 = __builtin_amdgcn_exp2f(s3 - mnew);
            float sum = (p0 + p1) + (p2 + p3);
            sum += __shfl_xor(sum, 1);
            sum += __shfl_xor(sum, 2);
            sum += __shfl_xor(sum, 4);
            sum += __shfl_xor(sum, 8);
            l_r[r] = l_r[r] * alpha + sum;
            m_r[r] = mnew;
#pragma unroll
            for (int cb = 0; cb < 8; ++cb) o[cb][r] *= alpha;
            // write P to per-wave LDS in a layout readable as an A-fragment
            int row = g * 4 + r;
            *(__bf16*)(PB + swz8(row * 128 + (0 * 16 + l15) * 2)) = (__bf16)p0;
            *(__bf16*)(PB + swz8(row * 128 + (1 * 16 + l15) * 2)) = (__bf16)p1;
            *(__bf16*)(PB + swz8(row * 128 + (2 * 16 + l15) * 2)) = (__bf16)p2;
            *(__bf16*)(PB + swz8(row * 128 + (3 * 16 + l15) * 2)) = (__bf16)p3;
        }

        // ---- PV: O += P(16x64) * V(64x128) ----
#pragma unroll
        for (int kk = 0; kk < 2; ++kk) {
            int pbyte = l15 * 128 + (kk * 32 + g * 8) * 2;
            bf16x8 pa = *(const bf16x8*)(PB + swz8(pbyte));
#pragma unroll
            for (int cb = 0; cb < 8; ++cb) {
                int vbyte = (cb * 16 + l15) * 128 + (kk * 32 + g * 8) * 2;
                bf16x8 vb = *(const bf16x8*)(VtB + swz8(vbyte));
                o[cb] = __builtin_amdgcn_mfma_f32_16x16x32_bf16(pa, vb, o[cb], 0, 0, 0);
            }
        }
    }

    // ---- epilogue: normalize and store fp32 ----
    float* Ob = Out + base + (long long)(qt * QTILE + w * 16) * DDIM;
#pragma unroll
    for (int r = 0; r < 4; ++r) {
        float inv = 1.0f / l_r[r];
        int row = g * 4 + r;
#pragma unroll
        for (int cb = 0; cb < 8; ++cb) {
            Ob[row * DDIM + cb * 16 + l15] = o[cb][r] * inv;
        }
    }
}

extern "C" void kernel_launch(void* const* d_in, const int* in_sizes, int n_in,
                              void* d_out, int out_size, void* d_ws, size_t ws_size,
                              hipStream_t stream) {
    const float* Q = (const float*)d_in[0];
    const float* K = (const float*)d_in[1];
    const float* V = (const float*)d_in[2];
    float* Out = (float*)d_out;
    dim3 grid(SEQ / QTILE, NBH);   // 32 x 32 = 1024 blocks
    dim3 block(256);
    attn_fwd_kernel<<<grid, block, 0, stream>>>(Q, K, V, Out);
}

// Round 2
// 131.636 us; speedup vs baseline: 5.5017x; 5.5017x over previous
//
#include <hip/hip_runtime.h>
#include <hip/hip_bf16.h>
#include <math.h>

#define SEQ   2048
#define DDIM  128
#define NBH   32
#define KVB   64
#define NT    (SEQ / KVB)        // 32 kv tiles
#define QTILE 128                // per block: 4 waves x 32 q-rows
#define QSCALE (0.08838834764831845f * 1.4426950408889634f)  // 1/sqrt(128) * log2(e)
#define THR_LOG2 8.0f            // defer-max threshold (log2 domain)

typedef __bf16 bf16x8 __attribute__((ext_vector_type(8)));
typedef float  f32x4  __attribute__((ext_vector_type(4)));
typedef unsigned short u16x8 __attribute__((ext_vector_type(8)));
typedef unsigned int   u32x4 __attribute__((ext_vector_type(4)));

// XOR swizzles (involutions). Ks tile byte = key*256 + d*2 ; Vt tile byte = d*128 + key*2
__device__ __forceinline__ int swz9(int b) { return b ^ (((b >> 9) & 7) << 4); }
__device__ __forceinline__ int swz8(int b) { return b ^ (((b >> 8) & 7) << 4); }

__device__ __forceinline__ void gload16(const void* g, void* l) {
    __builtin_amdgcn_global_load_lds(
        (const __attribute__((address_space(1))) unsigned int*)g,
        (__attribute__((address_space(3))) unsigned int*)l, 16, 0, 0);
}
__device__ __forceinline__ unsigned short bfb(float x) {
    return __builtin_bit_cast(unsigned short, (__bf16)x);
}
__device__ __forceinline__ bf16x8 cvt8s(float4 a, float4 b, float s) {
    bf16x8 v;
    v[0] = (__bf16)(a.x * s); v[1] = (__bf16)(a.y * s);
    v[2] = (__bf16)(a.z * s); v[3] = (__bf16)(a.w * s);
    v[4] = (__bf16)(b.x * s); v[5] = (__bf16)(b.y * s);
    v[6] = (__bf16)(b.z * s); v[7] = (__bf16)(b.w * s);
    return v;
}

// ---------------- prepass kernels ----------------

// Q: fp32 -> bf16, scale folded
__global__ __launch_bounds__(256)
void prep_q(const float* __restrict__ Q, __bf16* __restrict__ qws) {
    int id = blockIdx.x * 256 + threadIdx.x;       // 0 .. 1048575 ; 8 elems each
    const float* s = Q + (long long)id * 8;
    float4 a = *(const float4*)s;
    float4 b = *(const float4*)(s + 4);
    *(bf16x8*)(qws + (long long)id * 8) = cvt8s(a, b, QSCALE);
}

// K: fp32 -> bf16, with the Ks-LDS chunk swizzle baked into the global layout
__global__ __launch_bounds__(256)
void prep_k(const float* __restrict__ K, unsigned char* __restrict__ kws) {
    int id  = blockIdx.x * 256 + threadIdx.x;      // 0 .. 1048575 (16B chunks)
    int c   = id & 15;
    int row = id >> 4;                             // bh*2048 + key
    int key = row & (SEQ - 1);
    const float* s = K + (long long)row * 128 + c * 8;
    float4 a = *(const float4*)s;
    float4 b = *(const float4*)(s + 4);
    int c2 = c ^ ((key >> 1) & 7);                 // == swz9 on byte key*256 + c*16
    *(bf16x8*)(kws + (long long)row * 256 + c2 * 16) = cvt8s(a, b, 1.0f);
}

// V: fp32 [bh][key][d] -> bf16 Vt [bh][d][key] with Vt-LDS chunk swizzle baked
__global__ __launch_bounds__(256)
void prep_v(const float* __restrict__ V, unsigned char* __restrict__ vtws) {
    __shared__ float vt[64][129];                  // +1 pad: conflict-free col reads
    int kt = blockIdx.x, bh = blockIdx.y, tid = threadIdx.x;
#pragma unroll
    for (int it = 0; it < 4; ++it) {
        int chunk = tid + it * 256;                // 0..1023
        int key = chunk >> 4, c = chunk & 15;
        const float* s = V + ((long long)(bh * SEQ + kt * 64 + key)) * 128 + c * 8;
        float4 a = *(const float4*)s;
        float4 b = *(const float4*)(s + 4);
        vt[key][c * 8 + 0] = a.x; vt[key][c * 8 + 1] = a.y;
        vt[key][c * 8 + 2] = a.z; vt[key][c * 8 + 3] = a.w;
        vt[key][c * 8 + 4] = b.x; vt[key][c * 8 + 5] = b.y;
        vt[key][c * 8 + 6] = b.z; vt[key][c * 8 + 7] = b.w;
    }
    __syncthreads();
    int d = tid >> 1, half = tid & 1;
#pragma unroll
    for (int ch = 0; ch < 4; ++ch) {
        u16x8 u;
#pragma unroll
        for (int e = 0; e < 8; ++e) u[e] = bfb(vt[half * 32 + ch * 8 + e][d]);
        int c2 = (half * 4 + ch) ^ ((d >> 1) & 7); // == swz8 on byte d*128 + key*2
        *(u16x8*)(vtws + ((long long)(bh * 128 + d)) * 4096 + kt * 128 + c2 * 16) = u;
    }
}

// ---------------- main attention kernel (swapped-QK, dbuf, gload_lds) ----------------

__global__ __launch_bounds__(256, 2)
void attn_v2(const __bf16* __restrict__ qws, const unsigned char* __restrict__ kws,
             const unsigned char* __restrict__ vtws, float* __restrict__ Out) {
    __shared__ __align__(16) unsigned char lds[2][32768];   // per buf: Ks 16K | Vt 16K

    const int tid = threadIdx.x;
    const int lane = tid & 63;
    const int w = tid >> 6;
    const int l15 = lane & 15, g = lane >> 4;

    // bijective XCD swizzle: 512 blocks, 8 XCDs -> 64-block contiguous chunks (4 bh each)
    int bid = blockIdx.x;
    int swz = ((bid & 7) << 6) | (bid >> 3);
    const int qt = swz & 15;
    const int bh = swz >> 4;

    const unsigned char* kbh = kws + (long long)bh * 524288;
    const unsigned char* vbh = vtws + (long long)bh * 524288;

    // Q fragments: lane holds Q[q = rb*16+l15][d = ks*32 + g*8 + j]
    bf16x8 qf[2][4];
    const __bf16* qbase = qws + ((long long)bh * SEQ + qt * QTILE + w * 32) * DDIM;
#pragma unroll
    for (int rb = 0; rb < 2; ++rb)
#pragma unroll
        for (int ks = 0; ks < 4; ++ks)
            qf[rb][ks] = *(const bf16x8*)(qbase + (rb * 16 + l15) * DDIM + ks * 32 + g * 8);

    f32x4 o[2][8];
#pragma unroll
    for (int rb = 0; rb < 2; ++rb)
#pragma unroll
        for (int db = 0; db < 8; ++db) { o[rb][db][0]=0.f; o[rb][db][1]=0.f; o[rb][db][2]=0.f; o[rb][db][3]=0.f; }
    float m_r[2] = { -INFINITY, -INFINITY };
    float l_r[2] = { 0.f, 0.f };

    auto stage = [&](int buf, int kt) {
        unsigned char* Ksb = &lds[buf][0];
        unsigned char* Vtb = &lds[buf][16384];
        const unsigned char* ksrc = kbh + kt * 16384 + w * 4096 + (lane << 4);
#pragma unroll
        for (int i = 0; i < 4; ++i)
            gload16(ksrc + i * 1024, Ksb + w * 4096 + i * 1024);
#pragma unroll
        for (int i = 0; i < 4; ++i) {
            int d = w * 32 + i * 8 + (lane >> 3);
            gload16(vbh + d * 4096 + kt * 128 + ((lane & 7) << 4), Vtb + w * 4096 + i * 1024);
        }
    };

    stage(0, 0);
    __syncthreads();
    int cur = 0;

#pragma unroll 1
    for (int kt = 0; kt < NT; ++kt) {
        if (kt + 1 < NT) stage(cur ^ 1, kt + 1);   // prefetch next tile (in flight across compute)

        unsigned char* Ksb = &lds[cur][0];
        unsigned char* Vtb = &lds[cur][16384];

        // ---- swapped QK^T: St[key][q] = K . Q^T ; lane holds q=l15, keys c*16+g*4+r ----
        f32x4 sc[2][4];
#pragma unroll
        for (int rb = 0; rb < 2; ++rb)
#pragma unroll
            for (int c = 0; c < 4; ++c) { sc[rb][c][0]=0.f; sc[rb][c][1]=0.f; sc[rb][c][2]=0.f; sc[rb][c][3]=0.f; }
        __builtin_amdgcn_s_setprio(1);
#pragma unroll
        for (int c = 0; c < 4; ++c) {
#pragma unroll
            for (int ks = 0; ks < 4; ++ks) {
                bf16x8 kf = *(const bf16x8*)(Ksb + swz9((c * 16 + l15) * 256 + (ks * 32 + g * 8) * 2));
                sc[0][c] = __builtin_amdgcn_mfma_f32_16x16x32_bf16(kf, qf[0][ks], sc[0][c], 0, 0, 0);
                sc[1][c] = __builtin_amdgcn_mfma_f32_16x16x32_bf16(kf, qf[1][ks], sc[1][c], 0, 0, 0);
            }
        }
        __builtin_amdgcn_s_setprio(0);

        // ---- in-register online softmax + P repack to PV A-fragments ----
        u32x4 paw[2][2];
#pragma unroll
        for (int rb = 0; rb < 2; ++rb) {
            float s[16];
#pragma unroll
            for (int c = 0; c < 4; ++c)
#pragma unroll
                for (int r = 0; r < 4; ++r) s[c * 4 + r] = sc[rb][c][r];
            float m01 = fmaxf(s[0], s[1]),  m23 = fmaxf(s[2], s[3]);
            float m45 = fmaxf(s[4], s[5]),  m67 = fmaxf(s[6], s[7]);
            float m89 = fmaxf(s[8], s[9]),  mab = fmaxf(s[10], s[11]);
            float mcd = fmaxf(s[12], s[13]), mef = fmaxf(s[14], s[15]);
            float mx = fmaxf(fmaxf(fmaxf(m01, m23), fmaxf(m45, m67)),
                             fmaxf(fmaxf(m89, mab), fmaxf(mcd, mef)));
            mx = fmaxf(mx, __shfl_xor(mx, 16));
            mx = fmaxf(mx, __shfl_xor(mx, 32));
            float m = m_r[rb];
            if (!__all(mx <= m + THR_LOG2)) {      // defer-max: skip rescale on small growth
                float mnew = fmaxf(m, mx);
                float alpha = __builtin_amdgcn_exp2f(m - mnew);
                m_r[rb] = m = mnew;
                l_r[rb] *= alpha;
                float a0 = __shfl(alpha, g * 4 + 0), a1 = __shfl(alpha, g * 4 + 1);
                float a2 = __shfl(alpha, g * 4 + 2), a3 = __shfl(alpha, g * 4 + 3);
#pragma unroll
                for (int db = 0; db < 8; ++db) {
                    o[rb][db][0] *= a0; o[rb][db][1] *= a1; o[rb][db][2] *= a2; o[rb][db][3] *= a3;
                }
            }
            float p[16]; float sum = 0.f;
#pragma unroll
            for (int i = 0; i < 16; ++i) { p[i] = __builtin_amdgcn_exp2f(s[i] - m); sum += p[i]; }
            sum += __shfl_xor(sum, 16);
            sum += __shfl_xor(sum, 32);
            l_r[rb] += sum;
            // pack P pairs to bf16 dwords: dw[c*2+t] = keys (c*16+g*4+2t, +1) of q=l15
            unsigned int dw[8];
#pragma unroll
            for (int c = 0; c < 4; ++c) {
                dw[c * 2 + 0] = (unsigned)bfb(p[c * 4 + 0]) | ((unsigned)bfb(p[c * 4 + 1]) << 16);
                dw[c * 2 + 1] = (unsigned)bfb(p[c * 4 + 2]) | ((unsigned)bfb(p[c * 4 + 3]) << 16);
            }
            // redistribute: pa[ks2] dword tq = P[q=l15][keys ks2*32 + g*8 + 2tq, +1]
#pragma unroll
            for (int ks2 = 0; ks2 < 2; ++ks2) {
#pragma unroll
                for (int tq = 0; tq < 4; ++tq) {
                    int srcl = (((g & 1) * 2 + (tq >> 1)) << 4) + l15;
                    unsigned A = (unsigned)__shfl((int)dw[(2 * ks2) * 2 + (tq & 1)], srcl);
                    unsigned B = (unsigned)__shfl((int)dw[(2 * ks2 + 1) * 2 + (tq & 1)], srcl);
                    paw[rb][ks2][tq] = (g >> 1) ? B : A;
                }
            }
        }

        // ---- PV: O += P(32x64) . V(64x128) ----
        __builtin_amdgcn_s_setprio(1);
#pragma unroll
        for (int ks2 = 0; ks2 < 2; ++ks2) {
            bf16x8 pa0 = __builtin_bit_cast(bf16x8, paw[0][ks2]);
            bf16x8 pa1 = __builtin_bit_cast(bf16x8, paw[1][ks2]);
#pragma unroll
            for (int db = 0; db < 8; ++db) {
                bf16x8 vb = *(const bf16x8*)(Vtb + swz8((db * 16 + l15) * 128 + (ks2 * 32 + g * 8) * 2));
                o[0][db] = __builtin_amdgcn_mfma_f32_16x16x32_bf16(pa0, vb, o[0][db], 0, 0, 0);
                o[1][db] = __builtin_amdgcn_mfma_f32_16x16x32_bf16(pa1, vb, o[1][db], 0, 0, 0);
            }
        }
        __builtin_amdgcn_s_setprio(0);

        __syncthreads();   // drains vmcnt (next tile staged) + all reads of cur done
        cur ^= 1;
    }

    // ---- epilogue ----
    float* Ob = Out + ((long long)bh * SEQ + qt * QTILE + w * 32) * DDIM;
#pragma unroll
    for (int rb = 0; rb < 2; ++rb) {
        float inv = 1.0f / l_r[rb];
        float i0 = __shfl(inv, g * 4 + 0), i1 = __shfl(inv, g * 4 + 1);
        float i2 = __shfl(inv, g * 4 + 2), i3 = __shfl(inv, g * 4 + 3);
#pragma unroll
        for (int db = 0; db < 8; ++db) {
            int col = db * 16 + l15;
            Ob[(rb * 16 + g * 4 + 0) * DDIM + col] = o[rb][db][0] * i0;
            Ob[(rb * 16 + g * 4 + 1) * DDIM + col] = o[rb][db][1] * i1;
            Ob[(rb * 16 + g * 4 + 2) * DDIM + col] = o[rb][db][2] * i2;
            Ob[(rb * 16 + g * 4 + 3) * DDIM + col] = o[rb][db][3] * i3;
        }
    }
}

// ---------------- round-1 fallback (used only if ws_size too small) ----------------

__device__ __forceinline__ bf16x8 cvt8(float4 a, float4 b, float s) { return cvt8s(a, b, s); }

__global__ __launch_bounds__(256, 4)
void attn_fwd_v1(const float* __restrict__ Q, const float* __restrict__ K,
                 const float* __restrict__ V, float* __restrict__ Out) {
    __shared__ __align__(16) unsigned char lds[16384 + 16384 + 4 * 2048];
    unsigned char* KsB = lds;
    unsigned char* VtB = lds + 16384;
    const int tid = threadIdx.x;
    const int lane = tid & 63;
    const int w = tid >> 6;
    const int l15 = lane & 15;
    const int g = lane >> 4;
    const int qt = blockIdx.x;
    const int bh = blockIdx.y;
    const long long base = (long long)bh * SEQ * DDIM;
    const float* Qb = Q + base + (long long)(qt * 64 + w * 16) * DDIM;
    const float* Kb = K + base;
    const float* Vb = V + base;
    unsigned char* PB = lds + 32768 + w * 2048;
    bf16x8 qf[4];
#pragma unroll
    for (int ks = 0; ks < 4; ++ks) {
        const float* qp = Qb + l15 * DDIM + ks * 32 + g * 8;
        qf[ks] = cvt8(*(const float4*)qp, *(const float4*)(qp + 4), QSCALE);
    }
    f32x4 o[8];
#pragma unroll
    for (int cb = 0; cb < 8; ++cb) { o[cb][0]=0.f; o[cb][1]=0.f; o[cb][2]=0.f; o[cb][3]=0.f; }
    float m_r[4] = { -INFINITY, -INFINITY, -INFINITY, -INFINITY };
    float l_r[4] = { 0.f, 0.f, 0.f, 0.f };
    for (int kt = 0; kt < SEQ / KVB; ++kt) {
        __syncthreads();
#pragma unroll
        for (int it = 0; it < 4; ++it) {
            int chunk = tid + it * 256;
            int key = chunk >> 4;
            int dc = (chunk & 15) * 8;
            const float* kp = Kb + (long long)(kt * KVB + key) * DDIM + dc;
            *(bf16x8*)(KsB + swz9(key * 256 + dc * 2)) = cvt8(*(const float4*)kp, *(const float4*)(kp + 4), 1.0f);
        }
#pragma unroll
        for (int it = 0; it < 8; ++it) {
            int task = w + it * 4;
            int kq = task >> 1;
            int dh = task & 1;
            int key = kq * 4 + g;
            int d0 = dh * 64 + l15 * 4;
            const float* vp = Vb + (long long)(kt * KVB + key) * DDIM + d0;
            float4 a = *(const float4*)vp;
            *(__bf16*)(VtB + swz8((d0 + 0) * 128 + key * 2)) = (__bf16)a.x;
            *(__bf16*)(VtB + swz8((d0 + 1) * 128 + key * 2)) = (__bf16)a.y;
            *(__bf16*)(VtB + swz8((d0 + 2) * 128 + key * 2)) = (__bf16)a.z;
            *(__bf16*)(VtB + swz8((d0 + 3) * 128 + key * 2)) = (__bf16)a.w;
        }
        __syncthreads();
        f32x4 sc[4];
#pragma unroll
        for (int c = 0; c < 4; ++c) {
            f32x4 acc; acc[0]=0.f; acc[1]=0.f; acc[2]=0.f; acc[3]=0.f;
#pragma unroll
            for (int ks = 0; ks < 4; ++ks) {
                bf16x8 bf = *(const bf16x8*)(KsB + swz9((c * 16 + l15) * 256 + (ks * 32 + g * 8) * 2));
                acc = __builtin_amdgcn_mfma_f32_16x16x32_bf16(qf[ks], bf, acc, 0, 0, 0);
            }
            sc[c] = acc;
        }
#pragma unroll
        for (int r = 0; r < 4; ++r) {
            float s0 = sc[0][r], s1 = sc[1][r], s2 = sc[2][r], s3 = sc[3][r];
            float mx = fmaxf(fmaxf(s0, s1), fmaxf(s2, s3));
            mx = fmaxf(mx, __shfl_xor(mx, 1));
            mx = fmaxf(mx, __shfl_xor(mx, 2));
            mx = fmaxf(mx, __shfl_xor(mx, 4));
            mx = fmaxf(mx, __shfl_xor(mx, 8));
            float mold = m_r[r];
            float mnew = fmaxf(mold, mx);
            float alpha = __builtin_amdgcn_exp2f(mold - mnew);
            float p0 = __builtin_amdgcn_exp2f(s0 - mnew);
            float p1 = __builtin_amdgcn_exp2f(s1 - mnew);
            float p2 = __builtin_amdgcn_exp2f(s2 - mnew);
            float p3 = __builtin_amdgcn_exp2f(s3 - mnew);
            float sum = (p0 + p1) + (p2 + p3);
            sum += __shfl_xor(sum, 1);
            sum += __shfl_xor(sum, 2);
            sum += __shfl_xor(sum, 4);
            sum += __shfl_xor(sum, 8);
            l_r[r] = l_r[r] * alpha + sum;
            m_r[r] = mnew;
#pragma unroll
            for (int cb = 0; cb < 8; ++cb) o[cb][r] *= alpha;
            int row = g * 4 + r;
            *(__bf16*)(PB + swz8(row * 128 + (0 * 16 + l15) * 2)) = (__bf16)p0;
            *(__bf16*)(PB + swz8(row * 128 + (1 * 16 + l15) * 2)) = (__bf16)p1;
            *(__bf16*)(PB + swz8(row * 128 + (2 * 16 + l15) * 2)) = (__bf16)p2;
            *(__bf16*)(PB + swz8(row * 128 + (3 * 16 + l15) * 2)) = (__bf16)p3;
        }
#pragma unroll
        for (int kk = 0; kk < 2; ++kk) {
            bf16x8 pa = *(const bf16x8*)(PB + swz8(l15 * 128 + (kk * 32 + g * 8) * 2));
#pragma unroll
            for (int cb = 0; cb < 8; ++cb) {
                bf16x8 vb = *(const bf16x8*)(VtB + swz8((cb * 16 + l15) * 128 + (kk * 32 + g * 8) * 2));
                o[cb] = __builtin_amdgcn_mfma_f32_16x16x32_bf16(pa, vb, o[cb], 0, 0, 0);
            }
        }
    }
    float* Ob = Out + base + (long long)(qt * 64 + w * 16) * DDIM;
#pragma unroll
    for (int r = 0; r < 4; ++r) {
        float inv = 1.0f / l_r[r];
        int row = g * 4 + r;
#pragma unroll
        for (int cb = 0; cb < 8; ++cb) Ob[row * DDIM + cb * 16 + l15] = o[cb][r] * inv;
    }
}

extern "C" void kernel_launch(void* const* d_in, const int* in_sizes, int n_in,
                              void* d_out, int out_size, void* d_ws, size_t ws_size,
                              hipStream_t stream) {
    const float* Q = (const float*)d_in[0];
    const float* K = (const float*)d_in[1];
    const float* V = (const float*)d_in[2];
    float* Out = (float*)d_out;

    if (ws_size >= (size_t)48 * 1024 * 1024) {
        unsigned char* ws = (unsigned char*)d_ws;
        __bf16* qws = (__bf16*)ws;
        unsigned char* kws = ws + (size_t)16 * 1024 * 1024;
        unsigned char* vtws = ws + (size_t)32 * 1024 * 1024;
        prep_q<<<4096, 256, 0, stream>>>(Q, qws);
        prep_k<<<4096, 256, 0, stream>>>(K, kws);
        prep_v<<<dim3(32, 32), 256, 0, stream>>>(V, vtws);
        attn_v2<<<512, 256, 0, stream>>>(qws, kws, vtws, Out);
    } else {
        attn_fwd_v1<<<dim3(32, 32), 256, 0, stream>>>(Q, K, V, Out);
    }
}

// Round 3
// 126.306 us; speedup vs baseline: 5.7338x; 1.0422x over previous
//
#include <hip/hip_runtime.h>
#include <hip/hip_bf16.h>
#include <math.h>

#define SEQ   2048
#define DDIM  128
#define NBH   32
#define KVB   32
#define NT    (SEQ / KVB)        // 64 kv tiles
#define QSCALE (0.08838834764831845f * 1.4426950408889634f)  // 1/sqrt(128) * log2(e)
#define THR_LOG2 8.0f            // defer-max threshold (log2 domain)

typedef __bf16 bf16x8 __attribute__((ext_vector_type(8)));
typedef float  f32x4  __attribute__((ext_vector_type(4)));
typedef unsigned short u16x8 __attribute__((ext_vector_type(8)));

// Ks tile byte = key*256 + d*2 (key<32): XOR 16B-slot bits with (key>>1)&7
__device__ __forceinline__ int swz9(int b) { return b ^ (((b >> 9) & 7) << 4); }

__device__ __forceinline__ void gload16(const void* g, void* l) {
    __builtin_amdgcn_global_load_lds(
        (const __attribute__((address_space(1))) unsigned int*)g,
        (__attribute__((address_space(3))) unsigned int*)l, 16, 0, 0);
}
__device__ __forceinline__ unsigned short bfb(float x) {
    return __builtin_bit_cast(unsigned short, (__bf16)x);
}
__device__ __forceinline__ bf16x8 cvt8s(float4 a, float4 b, float s) {
    bf16x8 v;
    v[0] = (__bf16)(a.x * s); v[1] = (__bf16)(a.y * s);
    v[2] = (__bf16)(a.z * s); v[3] = (__bf16)(a.w * s);
    v[4] = (__bf16)(b.x * s); v[5] = (__bf16)(b.y * s);
    v[6] = (__bf16)(b.z * s); v[7] = (__bf16)(b.w * s);
    return v;
}

// ---------------- fused prepass: K -> bf16 (LDS-swizzle baked), V -> plain Vt bf16 ----------------
// grid 1024 x 256. Each block: (a) converts 16KB of K, (b) transposes one 64-key V group.
__global__ __launch_bounds__(256)
void prep_kv(const float* __restrict__ K, const float* __restrict__ V,
             unsigned char* __restrict__ kws, unsigned char* __restrict__ vtws) {
    const int blk = blockIdx.x, tid = threadIdx.x;

    // ---- K: fp32 -> bf16 rows of 256B with slot swizzle baked ----
#pragma unroll
    for (int it = 0; it < 4; ++it) {
        int chunk = blk * 1024 + it * 256 + tid;   // 0 .. 1048575 (16B chunks)
        int c   = chunk & 15;
        int row = chunk >> 4;                      // bh*2048 + key
        int key = row & (SEQ - 1);
        const float* s = K + (long long)row * DDIM + c * 8;
        float4 a = *(const float4*)s;
        float4 b = *(const float4*)(s + 4);
        int c2 = c ^ ((key >> 1) & 7);             // == swz9 on tile byte key_local*256 + c*16
        *(bf16x8*)(kws + (long long)row * 256 + c2 * 16) = cvt8s(a, b, 1.0f);
    }

    // ---- V: fp32 [bh][key][d] -> plain bf16 Vt [bh][d][key] (row 4096B) ----
    __shared__ float vt[64][129];
    const int kt64 = blk & 31, bh = blk >> 5;
#pragma unroll
    for (int it = 0; it < 4; ++it) {
        int chunk = tid + it * 256;                // 0..1023
        int key = chunk >> 4, c = chunk & 15;
        const float* s = V + ((long long)(bh * SEQ + kt64 * 64 + key)) * DDIM + c * 8;
        float4 a = *(const float4*)s;
        float4 b = *(const float4*)(s + 4);
        vt[key][c * 8 + 0] = a.x; vt[key][c * 8 + 1] = a.y;
        vt[key][c * 8 + 2] = a.z; vt[key][c * 8 + 3] = a.w;
        vt[key][c * 8 + 4] = b.x; vt[key][c * 8 + 5] = b.y;
        vt[key][c * 8 + 6] = b.z; vt[key][c * 8 + 7] = b.w;
    }
    __syncthreads();
    int d = tid >> 1, half = tid & 1;
#pragma unroll
    for (int ch = 0; ch < 4; ++ch) {
        u16x8 u;
#pragma unroll
        for (int e = 0; e < 8; ++e) u[e] = bfb(vt[half * 32 + ch * 8 + e][d]);
        *(u16x8*)(vtws + ((long long)(bh * 128 + d)) * 4096 + kt64 * 128 + (half * 4 + ch) * 16) = u;
    }
}

// ---------------- main attention kernel: 4 blocks/CU, KVB=32, swapped-QK ----------------

__global__ __launch_bounds__(256, 4)
void attn_v3(const float* __restrict__ Q, const unsigned char* __restrict__ kws,
             const unsigned char* __restrict__ vtws, float* __restrict__ Out) {
    __shared__ __align__(16) unsigned char lds[2][16384];   // per buf: Ks 8K | Vt 8K

    const int tid = threadIdx.x;
    const int lane = tid & 63;
    const int w = tid >> 6;
    const int l15 = lane & 15, g = lane >> 4;

    // bijective XCD swizzle: 1024 blocks -> 128-block chunks per XCD (4 bh each, K+V 4MB = L2)
    const int bid = blockIdx.x;
    const int swz = ((bid & 7) << 7) | (bid >> 3);
    const int qt = swz & 31;
    const int bh = swz >> 5;

    const unsigned char* kbh = kws + (long long)bh * 524288;
    const unsigned char* vbh = vtws + (long long)bh * 524288;

    // ---- Q fragments (fp32 -> bf16 in-register, scale folded) ----
    bf16x8 qf[4];
    const float* Qb = Q + ((long long)bh * SEQ + qt * 64 + w * 16 + l15) * DDIM;
#pragma unroll
    for (int ks = 0; ks < 4; ++ks) {
        const float* qp = Qb + ks * 32 + g * 8;
        qf[ks] = cvt8s(*(const float4*)qp, *(const float4*)(qp + 4), QSCALE);
    }

    f32x4 o[8];
#pragma unroll
    for (int db = 0; db < 8; ++db) { o[db][0]=0.f; o[db][1]=0.f; o[db][2]=0.f; o[db][3]=0.f; }
    float m_r = -INFINITY;
    float l_r = 0.f;          // per-lane partial (this lane's 8 keys/tile); cross-g reduce at end

    auto stage = [&](int buf, int kt) {
        unsigned char* Ksb = &lds[buf][0];
        unsigned char* Vtb = &lds[buf][8192];
#pragma unroll
        for (int i = 0; i < 2; ++i) {
            int sg = i * 256 + tid;                             // 16B chunk id, 0..511
            gload16(kbh + kt * 8192 + sg * 16, Ksb + sg * 16);  // Ks: linear copy (swz baked)
        }
#pragma unroll
        for (int i = 0; i < 2; ++i) {
            int sg = i * 256 + tid;
            int d = sg >> 2, s = sg & 3;
            // Vt: per-lane pre-swizzled SOURCE, linear LDS dest (both-sides rule)
            gload16(vbh + d * 4096 + kt * 64 + ((s ^ ((d >> 1) & 3)) << 4), Vtb + sg * 16);
        }
    };

    stage(0, 0);
    __syncthreads();
    int cur = 0;

#pragma unroll 1
    for (int kt = 0; kt < NT; ++kt) {
        if (kt + 1 < NT) stage(cur ^ 1, kt + 1);   // prefetch next tile; lands before next barrier

        unsigned char* Ksb = &lds[cur][0];
        unsigned char* Vtb = &lds[cur][8192];

        // ---- swapped QK^T: D[key][q]; lane holds q=l15, keys c*16 + g*4 + r ----
        f32x4 sc[2];
#pragma unroll
        for (int c = 0; c < 2; ++c) { sc[c][0]=0.f; sc[c][1]=0.f; sc[c][2]=0.f; sc[c][3]=0.f; }
        __builtin_amdgcn_s_setprio(1);
#pragma unroll
        for (int c = 0; c < 2; ++c)
#pragma unroll
            for (int ks = 0; ks < 4; ++ks) {
                bf16x8 kf = *(const bf16x8*)(Ksb + swz9((c * 16 + l15) * 256 + ks * 64 + g * 16));
                sc[c] = __builtin_amdgcn_mfma_f32_16x16x32_bf16(kf, qf[ks], sc[c], 0, 0, 0);
            }
        __builtin_amdgcn_s_setprio(0);

        // ---- in-register online softmax (defer-max; lazy cross-lane max) ----
        float s[8];
#pragma unroll
        for (int c = 0; c < 2; ++c)
#pragma unroll
            for (int r = 0; r < 4; ++r) s[c * 4 + r] = sc[c][r];
        float mx = fmaxf(fmaxf(fmaxf(s[0], s[1]), fmaxf(s[2], s[3])),
                         fmaxf(fmaxf(s[4], s[5]), fmaxf(s[6], s[7])));
        if (!__all(mx <= m_r + THR_LOG2)) {
            float mxg = fmaxf(mx, __shfl_xor(mx, 16));
            mxg = fmaxf(mxg, __shfl_xor(mxg, 32));
            float mnew = fmaxf(m_r, mxg);
            float alpha = __builtin_amdgcn_exp2f(m_r - mnew);
            m_r = mnew;
            l_r *= alpha;
            float a0 = __shfl(alpha, g * 4 + 0), a1 = __shfl(alpha, g * 4 + 1);
            float a2 = __shfl(alpha, g * 4 + 2), a3 = __shfl(alpha, g * 4 + 3);
#pragma unroll
            for (int db = 0; db < 8; ++db) {
                o[db][0] *= a0; o[db][1] *= a1; o[db][2] *= a2; o[db][3] *= a3;
            }
        }
        float p[8]; float sum = 0.f;
#pragma unroll
        for (int i = 0; i < 8; ++i) { p[i] = __builtin_amdgcn_exp2f(s[i] - m_r); sum += p[i]; }
        l_r += sum;

        // ---- P repack: c-layout (keys c*16+g*4+r) -> A-frag (keys g*8+j) ----
        unsigned int dw[4];
#pragma unroll
        for (int c = 0; c < 2; ++c) {
            dw[c * 2 + 0] = (unsigned)bfb(p[c * 4 + 0]) | ((unsigned)bfb(p[c * 4 + 1]) << 16);
            dw[c * 2 + 1] = (unsigned)bfb(p[c * 4 + 2]) | ((unsigned)bfb(p[c * 4 + 3]) << 16);
        }
        unsigned int pw[4];
#pragma unroll
        for (int t = 0; t < 4; ++t) {
            int srcl = (((g & 1) * 2 + (t >> 1)) << 4) + l15;
            unsigned A = (unsigned)__shfl((int)dw[t & 1], srcl);
            unsigned B = (unsigned)__shfl((int)dw[2 + (t & 1)], srcl);
            pw[t] = (g >> 1) ? B : A;
        }
        bf16x8 pa;
        {
            unsigned int tmp[4] = { pw[0], pw[1], pw[2], pw[3] };
            pa = *(bf16x8*)tmp;
        }

        // ---- PV: O += P(16x32) . V(32x128) ----
        __builtin_amdgcn_s_setprio(1);
#pragma unroll
        for (int db = 0; db < 8; ++db) {
            int d = db * 16 + l15;
            bf16x8 vb = *(const bf16x8*)(Vtb + d * 64 + ((g ^ ((d >> 1) & 3)) << 4));
            o[db] = __builtin_amdgcn_mfma_f32_16x16x32_bf16(pa, vb, o[db], 0, 0, 0);
        }
        __builtin_amdgcn_s_setprio(0);

        __syncthreads();   // prefetch landed + all reads of cur done
        cur ^= 1;
    }

    // ---- epilogue: cross-g l reduce, normalize, store fp32 ----
    l_r += __shfl_xor(l_r, 16);
    l_r += __shfl_xor(l_r, 32);
    float inv = 1.0f / l_r;
    float i0 = __shfl(inv, g * 4 + 0), i1 = __shfl(inv, g * 4 + 1);
    float i2 = __shfl(inv, g * 4 + 2), i3 = __shfl(inv, g * 4 + 3);
    float* Ob = Out + ((long long)bh * SEQ + qt * 64 + w * 16) * DDIM;
#pragma unroll
    for (int db = 0; db < 8; ++db) {
        int col = db * 16 + l15;
        Ob[(g * 4 + 0) * DDIM + col] = o[db][0] * i0;
        Ob[(g * 4 + 1) * DDIM + col] = o[db][1] * i1;
        Ob[(g * 4 + 2) * DDIM + col] = o[db][2] * i2;
        Ob[(g * 4 + 3) * DDIM + col] = o[db][3] * i3;
    }
}

// ---------------- fallback (used only if ws_size too small) ----------------

__device__ __forceinline__ int swz8f(int b) { return b ^ (((b >> 8) & 7) << 4); }

__global__ __launch_bounds__(256, 4)
void attn_fwd_v1(const float* __restrict__ Q, const float* __restrict__ K,
                 const float* __restrict__ V, float* __restrict__ Out) {
    __shared__ __align__(16) unsigned char lds[16384 + 16384 + 4 * 2048];
    unsigned char* KsB = lds;
    unsigned char* VtB = lds + 16384;
    const int tid = threadIdx.x;
    const int lane = tid & 63;
    const int w = tid >> 6;
    const int l15 = lane & 15;
    const int g = lane >> 4;
    const int qt = blockIdx.x;
    const int bh = blockIdx.y;
    const long long base = (long long)bh * SEQ * DDIM;
    const float* Qb = Q + base + (long long)(qt * 64 + w * 16) * DDIM;
    const float* Kb = K + base;
    const float* Vb = V + base;
    unsigned char* PB = lds + 32768 + w * 2048;
    bf16x8 qf[4];
#pragma unroll
    for (int ks = 0; ks < 4; ++ks) {
        const float* qp = Qb + l15 * DDIM + ks * 32 + g * 8;
        qf[ks] = cvt8s(*(const float4*)qp, *(const float4*)(qp + 4), QSCALE);
    }
    f32x4 o[8];
#pragma unroll
    for (int cb = 0; cb < 8; ++cb) { o[cb][0]=0.f; o[cb][1]=0.f; o[cb][2]=0.f; o[cb][3]=0.f; }
    float m_r[4] = { -INFINITY, -INFINITY, -INFINITY, -INFINITY };
    float l_r[4] = { 0.f, 0.f, 0.f, 0.f };
    for (int kt = 0; kt < SEQ / 64; ++kt) {
        __syncthreads();
#pragma unroll
        for (int it = 0; it < 4; ++it) {
            int chunk = tid + it * 256;
            int key = chunk >> 4;
            int dc = (chunk & 15) * 8;
            const float* kp = Kb + (long long)(kt * 64 + key) * DDIM + dc;
            *(bf16x8*)(KsB + swz9(key * 256 + dc * 2)) = cvt8s(*(const float4*)kp, *(const float4*)(kp + 4), 1.0f);
        }
#pragma unroll
        for (int it = 0; it < 8; ++it) {
            int task = w + it * 4;
            int kq = task >> 1;
            int dh = task & 1;
            int key = kq * 4 + g;
            int d0 = dh * 64 + l15 * 4;
            const float* vp = Vb + (long long)(kt * 64 + key) * DDIM + d0;
            float4 a = *(const float4*)vp;
            *(__bf16*)(VtB + swz8f((d0 + 0) * 128 + key * 2)) = (__bf16)a.x;
            *(__bf16*)(VtB + swz8f((d0 + 1) * 128 + key * 2)) = (__bf16)a.y;
            *(__bf16*)(VtB + swz8f((d0 + 2) * 128 + key * 2)) = (__bf16)a.z;
            *(__bf16*)(VtB + swz8f((d0 + 3) * 128 + key * 2)) = (__bf16)a.w;
        }
        __syncthreads();
        f32x4 sc[4];
#pragma unroll
        for (int c = 0; c < 4; ++c) {
            f32x4 acc; acc[0]=0.f; acc[1]=0.f; acc[2]=0.f; acc[3]=0.f;
#pragma unroll
            for (int ks = 0; ks < 4; ++ks) {
                bf16x8 bf = *(const bf16x8*)(KsB + swz9((c * 16 + l15) * 256 + (ks * 32 + g * 8) * 2));
                acc = __builtin_amdgcn_mfma_f32_16x16x32_bf16(qf[ks], bf, acc, 0, 0, 0);
            }
            sc[c] = acc;
        }
#pragma unroll
        for (int r = 0; r < 4; ++r) {
            float s0 = sc[0][r], s1 = sc[1][r], s2 = sc[2][r], s3 = sc[3][r];
            float mx = fmaxf(fmaxf(s0, s1), fmaxf(s2, s3));
            mx = fmaxf(mx, __shfl_xor(mx, 1));
            mx = fmaxf(mx, __shfl_xor(mx, 2));
            mx = fmaxf(mx, __shfl_xor(mx, 4));
            mx = fmaxf(mx, __shfl_xor(mx, 8));
            float mold = m_r[r];
            float mnew = fmaxf(mold, mx);
            float alpha = __builtin_amdgcn_exp2f(mold - mnew);
            float p0 = __builtin_amdgcn_exp2f(s0 - mnew);
            float p1 = __builtin_amdgcn_exp2f(s1 - mnew);
            float p2 = __builtin_amdgcn_exp2f(s2 - mnew);
            float p3 = __builtin_amdgcn_exp2f(s3 - mnew);
            float sum = (p0 + p1) + (p2 + p3);
            sum += __shfl_xor(sum, 1);
            sum += __shfl_xor(sum, 2);
            sum += __shfl_xor(sum, 4);
            sum += __shfl_xor(sum, 8);
            l_r[r] = l_r[r] * alpha + sum;
            m_r[r] = mnew;
#pragma unroll
            for (int cb = 0; cb < 8; ++cb) o[cb][r] *= alpha;
            int row = g * 4 + r;
            *(__bf16*)(PB + swz8f(row * 128 + (0 * 16 + l15) * 2)) = (__bf16)p0;
            *(__bf16*)(PB + swz8f(row * 128 + (1 * 16 + l15) * 2)) = (__bf16)p1;
            *(__bf16*)(PB + swz8f(row * 128 + (2 * 16 + l15) * 2)) = (__bf16)p2;
            *(__bf16*)(PB + swz8f(row * 128 + (3 * 16 + l15) * 2)) = (__bf16)p3;
        }
#pragma unroll
        for (int kk = 0; kk < 2; ++kk) {
            bf16x8 pa = *(const bf16x8*)(PB + swz8f(l15 * 128 + (kk * 32 + g * 8) * 2));
#pragma unroll
            for (int cb = 0; cb < 8; ++cb) {
                bf16x8 vb = *(const bf16x8*)(VtB + swz8f((cb * 16 + l15) * 128 + (kk * 32 + g * 8) * 2));
                o[cb] = __builtin_amdgcn_mfma_f32_16x16x32_bf16(pa, vb, o[cb], 0, 0, 0);
            }
        }
    }
    float* Ob = Out + base + (long long)(qt * 64 + w * 16) * DDIM;
#pragma unroll
    for (int r = 0; r < 4; ++r) {
        float inv = 1.0f / l_r[r];
        int row = g * 4 + r;
#pragma unroll
        for (int cb = 0; cb < 8; ++cb) Ob[row * DDIM + cb * 16 + l15] = o[cb][r] * inv;
    }
}

extern "C" void kernel_launch(void* const* d_in, const int* in_sizes, int n_in,
                              void* d_out, int out_size, void* d_ws, size_t ws_size,
                              hipStream_t stream) {
    const float* Q = (const float*)d_in[0];
    const float* K = (const float*)d_in[1];
    const float* V = (const float*)d_in[2];
    float* Out = (float*)d_out;

    if (ws_size >= (size_t)32 * 1024 * 1024) {
        unsigned char* ws = (unsigned char*)d_ws;
        unsigned char* kws = ws;
        unsigned char* vtws = ws + (size_t)16 * 1024 * 1024;
        prep_kv<<<1024, 256, 0, stream>>>(K, V, kws, vtws);
        attn_v3<<<1024, 256, 0, stream>>>(Q, kws, vtws, Out);
    } else {
        attn_fwd_v1<<<dim3(32, 32), 256, 0, stream>>>(Q, K, V, Out);
    }
}